// Round 15
// baseline (116.866 us; speedup 1.0000x reference)
//
#include <hip/hip_runtime.h>

#define HH 128
#define BU 8        // user buckets (one per XCD)
#define BI 32       // item sub-buckets
#define NBKT (BU * BI)
#define SCHUNK 2048 // edges per scatter block
#define GPUC 16384  // edge-kernel 4-lane groups per uc (2048 blocks * 64 / 8)

typedef __attribute__((ext_vector_type(8))) short bf16x8;
typedef __attribute__((ext_vector_type(4))) float f32x4;
typedef _Float16 h2 __attribute__((ext_vector_type(2)));

#if __has_builtin(__builtin_amdgcn_fdot2)
#define FDOT2(a, b, c) __builtin_amdgcn_fdot2((a), (b), (c), false)
#else
#define FDOT2(a, b, c) ((c) + (float)(a)[0] * (float)(b)[0] + (float)(a)[1] * (float)(b)[1])
#endif

__device__ inline unsigned short f2bf(float f) {
    unsigned u = __builtin_bit_cast(unsigned, f);
    u += 0x7FFF + ((u >> 16) & 1);
    return (unsigned short)(u >> 16);
}
__device__ inline unsigned short f2h(float f) {
    return __builtin_bit_cast(unsigned short, (_Float16)f);
}

// ============ prep: blocks 0..15 transpose W -> Wt (SWIZZLED layout); rest: fixed-cap scatter ==
// Wt[h][c*128 + ((kc ^ (c&15))<<3) + (k&7)] = bf16(W1[h*128+k][c])
__global__ __launch_bounds__(256) void prep_kernel(
    const float* __restrict__ W1, unsigned short* __restrict__ Wt,
    const int* __restrict__ row, const int* __restrict__ col,
    unsigned* __restrict__ cursor, unsigned* __restrict__ srt,
    unsigned* __restrict__ invpos, int E, unsigned n_user, unsigned n_item, int cap)
{
    const int t = threadIdx.x;
    if ((int)blockIdx.x < 16) {
        const int gid = blockIdx.x * 256 + t;   // 0..4095
        const int h   = gid >> 11;
        const int c   = (gid >> 4) & 127;
        const int kc  = gid & 15;
        const float* src = W1 + (size_t)(h * 128 + kc * 8) * HH + c;
        unsigned short v[8];
        #pragma unroll
        for (int d = 0; d < 8; ++d)
            v[d] = f2bf(src[(size_t)d * HH]);
        uint4 pack;
        pack.x = (unsigned)v[0] | ((unsigned)v[1] << 16);
        pack.y = (unsigned)v[2] | ((unsigned)v[3] << 16);
        pack.z = (unsigned)v[4] | ((unsigned)v[5] << 16);
        pack.w = (unsigned)v[6] | ((unsigned)v[7] << 16);
        *(uint4*)(Wt + (size_t)h * 16384 + c * 128 + ((kc ^ (c & 15)) << 3)) = pack;
        return;
    }
    // ---- scatter: two-pass block-local LDS binning into fixed-capacity buckets ----
    __shared__ unsigned lh[NBKT];
    __shared__ unsigned gb[NBKT];
    __shared__ unsigned lc[NBKT];
    const int base = ((int)blockIdx.x - 16) * SCHUNK;

    int uu[SCHUNK / 256], ii[SCHUNK / 256];
    lh[t] = 0;
    __syncthreads();
    #pragma unroll
    for (int k = 0; k < SCHUNK / 256; ++k) {
        int e = base + k * 256 + t;
        if (e < E) {
            uu[k] = row[e]; ii[k] = col[e];
            unsigned uc = ((unsigned)uu[k] * BU) / n_user;
            unsigned ic = ((unsigned)ii[k] * BI) / n_item;
            atomicAdd(&lh[uc * BI + ic], 1u);
        }
    }
    __syncthreads();
    gb[t] = lh[t] ? (unsigned)(t * cap) + atomicAdd(&cursor[t], lh[t]) : 0u;
    lc[t] = 0;
    __syncthreads();
    #pragma unroll
    for (int k = 0; k < SCHUNK / 256; ++k) {
        int e = base + k * 256 + t;
        if (e < E) {
            unsigned uc = ((unsigned)uu[k] * BU) / n_user;
            unsigned ic = ((unsigned)ii[k] * BI) / n_item;
            int b = (int)(uc * BI + ic);
            unsigned ucbase = (uc * n_user + 7u) >> 3;
            unsigned r   = atomicAdd(&lc[b], 1u);
            unsigned pos = gb[b] + r;
            srt[pos]  = (((unsigned)uu[k] - ucbase) << 16) | (unsigned)ii[k];
            invpos[e] = pos;
        }
    }
}

// ============ projection: linear LDS stage of pre-swizzled Wt, conflict-free MFMA, fp16 out ====
__global__ __launch_bounds__(256) void project_kernel(
    const float* __restrict__ Zu, const float* __restrict__ Zi,
    const unsigned short* __restrict__ Wt, const float* __restrict__ b1,
    unsigned short* __restrict__ Pu, unsigned short* __restrict__ Pi,
    int n_user, int n_item, int utiles, int itiles)
{
    __shared__ unsigned short sWt[128 * 128];    // 32 KB, swizzle baked into Wt
    __shared__ unsigned short sOut[64 * 136];    // 17 KB

    const int t    = threadIdx.x;
    const int wave = t >> 6;
    const int lane = t & 63;
    const int l16  = lane & 15;
    const int lk8  = (lane >> 4) * 8;
    const int total = utiles + itiles;

    int staged = -1;

    for (int tid = blockIdx.x; tid < total; tid += gridDim.x) {
        const bool isUser = (tid < utiles);
        const int  half   = isUser ? 0 : 1;
        const float* __restrict__ Z = isUser ? Zu : Zi;
        unsigned short* __restrict__ P = isUser ? Pu : Pi;
        const int nrows = isUser ? n_user : n_item;
        const int rbase = (isUser ? tid : (tid - utiles)) << 6;

        if (half != staged) {
            __syncthreads();              // everyone done with old sWt
            const unsigned short* src = Wt + (size_t)half * 16384;
            #pragma unroll
            for (int i = 0; i < 16; ++i) {
                int off = (i * 256 + t) * 8;
                *(uint4*)(sWt + off) = *(const uint4*)(src + off);
            }
            __syncthreads();
            staged = half;
        }

        float b1r[8];
        #pragma unroll
        for (int nt = 0; nt < 8; ++nt)
            b1r[nt] = isUser ? b1[nt * 16 + l16] : 0.f;

        f32x4 acc[8];
        #pragma unroll
        for (int nt = 0; nt < 8; ++nt) acc[nt] = (f32x4)0.f;

        int m = rbase + wave * 16 + l16;
        if (m > nrows - 1) m = nrows - 1;      // clamp tail (stores guarded)
        const float* Zrow = Z + (size_t)m * HH;

        #pragma unroll
        for (int kk = 0; kk < 4; ++kk) {
            float4 z0 = *(const float4*)(Zrow + kk * 32 + lk8);
            float4 z1 = *(const float4*)(Zrow + kk * 32 + lk8 + 4);
            bf16x8 a;
            a[0] = (short)f2bf(z0.x); a[1] = (short)f2bf(z0.y);
            a[2] = (short)f2bf(z0.z); a[3] = (short)f2bf(z0.w);
            a[4] = (short)f2bf(z1.x); a[5] = (short)f2bf(z1.y);
            a[6] = (short)f2bf(z1.z); a[7] = (short)f2bf(z1.w);

            const int chunkSw = ((kk * 4 + (lane >> 4)) ^ l16) << 3;
            #pragma unroll
            for (int nt = 0; nt < 8; ++nt) {
                int c = nt * 16 + l16;
                bf16x8 b = *(const bf16x8*)(sWt + c * 128 + chunkSw);
                acc[nt] = __builtin_amdgcn_mfma_f32_16x16x32_bf16(a, b, acc[nt], 0, 0, 0);
            }
        }

        __syncthreads();   // sOut safe to overwrite
        #pragma unroll
        for (int nt = 0; nt < 8; ++nt) {
            int colc = nt * 16 + l16;
            #pragma unroll
            for (int r = 0; r < 4; ++r) {
                int orow = wave * 16 + (lane >> 4) * 4 + r;
                sOut[orow * 136 + colc] = f2h(acc[nt][r] + b1r[nt]);
            }
        }
        __syncthreads();
        #pragma unroll
        for (int i = 0; i < 4; ++i) {
            int idx = t + i * 256;
            int r   = idx >> 4;
            int ch  = idx & 15;
            int grow = rbase + r;
            if (grow < nrows)
                *(uint4*)(P + (size_t)grow * HH + ch * 8) =
                    *(const uint4*)(sOut + r * 136 + ch * 8);
        }
    }
}

// ============ edge kernel: 4 lanes/edge (64B/lane), 16 edges/wave for MLP ============
__global__ __launch_bounds__(256) void edge_sorted_kernel(
    const unsigned short* __restrict__ Pu, const unsigned short* __restrict__ Pi,
    const unsigned* __restrict__ srt, const unsigned* __restrict__ cursor,
    const float* __restrict__ W2, const float* __restrict__ b2,
    float* __restrict__ psorted, int cap, int n_user)
{
    const int uc     = blockIdx.x & (BU - 1);
    const int jj     = blockIdx.x >> 3;          // 0..255
    const int g      = threadIdx.x >> 2;         // 0..63
    const int lane4  = threadIdx.x & 3;
    const int gg     = jj * 64 + g;              // 0..16383
    const int c0     = lane4 * 32;               // 32 channels = 64B per lane
    const int ucbase = (int)(((unsigned)uc * (unsigned)n_user + 7u) >> 3);

    h2 w2h[16];
    #pragma unroll
    for (int j = 0; j < 16; ++j) {
        w2h[j][0] = (_Float16)W2[c0 + 2 * j];
        w2h[j][1] = (_Float16)W2[c0 + 2 * j + 1];
    }
    const float b2s = b2[0];
    const h2 hz = {(_Float16)0, (_Float16)0};

    #pragma unroll 1
    for (int ic = 0; ic < BI; ++ic) {
        const int b    = uc * BI + ic;
        const int S    = b * cap;
        const int Tend = S + (int)cursor[b];
        for (int p = S + gg; p < Tend; p += GPUC) {
            unsigned pk = srt[p];
            int u  = ucbase + (int)(pk >> 16);
            int it = (int)(pk & 0xFFFFu);
            const unsigned short* pur = Pu + (size_t)u  * HH + c0;
            const unsigned short* pir = Pi + (size_t)it * HH + c0;
            uint4 a0 = *(const uint4*)pur;
            uint4 a1 = *(const uint4*)(pur + 8);
            uint4 a2 = *(const uint4*)(pur + 16);
            uint4 a3 = *(const uint4*)(pur + 24);
            uint4 d0 = *(const uint4*)pir;
            uint4 d1 = *(const uint4*)(pir + 8);
            uint4 d2 = *(const uint4*)(pir + 16);
            uint4 d3 = *(const uint4*)(pir + 24);
            unsigned aw[16] = {a0.x, a0.y, a0.z, a0.w, a1.x, a1.y, a1.z, a1.w,
                               a2.x, a2.y, a2.z, a2.w, a3.x, a3.y, a3.z, a3.w};
            unsigned cw[16] = {d0.x, d0.y, d0.z, d0.w, d1.x, d1.y, d1.z, d1.w,
                               d2.x, d2.y, d2.z, d2.w, d3.x, d3.y, d3.z, d3.w};
            float acc = 0.f;
            #pragma unroll
            for (int q = 0; q < 16; ++q) {
                h2 s = __builtin_bit_cast(h2, aw[q]) + __builtin_bit_cast(h2, cw[q]);
                s = __builtin_elementwise_max(s, hz);
                acc = FDOT2(s, w2h[q], acc);
            }
            acc += __shfl_xor(acc, 2, 64);
            acc += __shfl_xor(acc, 1, 64);
            if (lane4 == 0) psorted[p] = acc + b2s;
        }
    }
}

// ============ permutation: out[e] = psorted[invpos[e]] ============
__global__ __launch_bounds__(256) void permute_kernel(
    const float* __restrict__ psorted, const unsigned* __restrict__ invpos,
    float* __restrict__ out, int E)
{
    int i  = blockIdx.x * blockDim.x + threadIdx.x;
    int st = gridDim.x * blockDim.x;
    for (int e = i; e < E; e += st)
        out[e] = psorted[invpos[e]];
}

// ============ fallback: unsorted fp16 gather ============
__global__ __launch_bounds__(256) void edge_fp16_kernel(
    const unsigned short* __restrict__ Pu, const unsigned short* __restrict__ Pi,
    const int* __restrict__ row, const int* __restrict__ col,
    const float* __restrict__ W2, const float* __restrict__ b2,
    float* __restrict__ out, int E)
{
    const int lane8  = threadIdx.x & 7;
    const int gid    = (blockIdx.x * blockDim.x + threadIdx.x) >> 3;
    const int stride = (gridDim.x * blockDim.x) >> 3;
    const int c0     = lane8 * 16;

    h2 w2h[8];
    #pragma unroll
    for (int j = 0; j < 8; ++j) {
        w2h[j][0] = (_Float16)W2[c0 + 2 * j];
        w2h[j][1] = (_Float16)W2[c0 + 2 * j + 1];
    }
    const float b2s = b2[0];
    const h2 hz = {(_Float16)0, (_Float16)0};

    for (int e = gid; e < E; e += stride) {
        int u = row[e], it = col[e];
        const unsigned short* pur = Pu + (size_t)u  * HH + c0;
        const unsigned short* pir = Pi + (size_t)it * HH + c0;
        uint4 a0 = *(const uint4*)pur;
        uint4 a1 = *(const uint4*)(pur + 8);
        uint4 c0v = *(const uint4*)pir;
        uint4 c1v = *(const uint4*)(pir + 8);
        unsigned aw[8] = {a0.x, a0.y, a0.z, a0.w, a1.x, a1.y, a1.z, a1.w};
        unsigned cw[8] = {c0v.x, c0v.y, c0v.z, c0v.w, c1v.x, c1v.y, c1v.z, c1v.w};
        float acc = 0.f;
        #pragma unroll
        for (int q = 0; q < 8; ++q) {
            h2 s = __builtin_bit_cast(h2, aw[q]) + __builtin_bit_cast(h2, cw[q]);
            s = __builtin_elementwise_max(s, hz);
            acc = FDOT2(s, w2h[q], acc);
        }
        acc += __shfl_xor(acc, 4, 64);
        acc += __shfl_xor(acc, 2, 64);
        acc += __shfl_xor(acc, 1, 64);
        if (lane8 == 0) out[e] = acc + b2s;
    }
}

// ============ fallback (no workspace): direct per-edge fp32 compute ============
__global__ __launch_bounds__(256) void edge_direct_kernel(
    const float* __restrict__ zu, const float* __restrict__ zi,
    const int* __restrict__ row, const int* __restrict__ col,
    const float* __restrict__ W1, const float* __restrict__ b1,
    const float* __restrict__ W2, const float* __restrict__ b2,
    float* __restrict__ out, int E)
{
    const int lane   = threadIdx.x & 31;
    const int gid    = (blockIdx.x * blockDim.x + threadIdx.x) >> 5;
    const int stride = (gridDim.x * blockDim.x) >> 5;
    const int c0     = lane * 4;

    const float4 b1v = *(const float4*)(b1 + c0);
    const float4 w2v = *(const float4*)(W2 + c0);
    const float  b2s = b2[0];

    for (int e = gid; e < E; e += stride) {
        int u  = row[e];
        int it = col[e];
        const float* zur = zu + (size_t)u  * HH;
        const float* zir = zi + (size_t)it * HH;
        float4 acc = b1v;
        for (int k = 0; k < HH; ++k) {
            float  zk = zur[k];
            float4 w  = *(const float4*)(W1 + (size_t)k * HH + c0);
            acc.x = fmaf(zk, w.x, acc.x);
            acc.y = fmaf(zk, w.y, acc.y);
            acc.z = fmaf(zk, w.z, acc.z);
            acc.w = fmaf(zk, w.w, acc.w);
        }
        for (int k = 0; k < HH; ++k) {
            float  zk = zir[k];
            float4 w  = *(const float4*)(W1 + (size_t)(HH + k) * HH + c0);
            acc.x = fmaf(zk, w.x, acc.x);
            acc.y = fmaf(zk, w.y, acc.y);
            acc.z = fmaf(zk, w.z, acc.z);
            acc.w = fmaf(zk, w.w, acc.w);
        }
        float p = fmaxf(acc.x, 0.f) * w2v.x;
        p = fmaf(fmaxf(acc.y, 0.f), w2v.y, p);
        p = fmaf(fmaxf(acc.z, 0.f), w2v.z, p);
        p = fmaf(fmaxf(acc.w, 0.f), w2v.w, p);
        #pragma unroll
        for (int m = 16; m >= 1; m >>= 1)
            p += __shfl_xor(p, m, 64);
        if (lane == 0) out[e] = p + b2s;
    }
}

static inline size_t align256(size_t x) { return (x + 255) & ~(size_t)255; }

extern "C" void kernel_launch(void* const* d_in, const int* in_sizes, int n_in,
                              void* d_out, int out_size, void* d_ws, size_t ws_size,
                              hipStream_t stream)
{
    const float* z_user = (const float*)d_in[0];
    const float* z_item = (const float*)d_in[1];
    const int*   row    = (const int*)d_in[2];
    const int*   col    = (const int*)d_in[3];
    const float* W1     = (const float*)d_in[4];
    const float* b1     = (const float*)d_in[5];
    const float* W2     = (const float*)d_in[6];
    const float* b2     = (const float*)d_in[7];
    float*       out    = (float*)d_out;

    const int n_user = in_sizes[0] / HH;
    const int n_item = in_sizes[1] / HH;
    const int E      = in_sizes[2];

    // fixed-capacity bucket regions: cap = 1.25*mean + 64
    const int capBase = (E + NBKT - 1) / NBKT;
    const int cap     = capBase + capBase / 4 + 64;
    const size_t padded = (size_t)cap * NBKT;

    // workspace layout
    const size_t offWt  = 0;                                   // 64 KB bf16 W^T (swizzled)
    const size_t offPu  = align256(offWt  + 32768 * 2);
    const size_t offPi  = align256(offPu  + (size_t)n_user * HH * 2);
    const size_t offSrt = align256(offPi  + (size_t)n_item * HH * 2);
    const size_t offPs  = align256(offSrt + padded * 4);
    const size_t offInv = align256(offPs  + padded * 4);
    const size_t offCur = align256(offInv + (size_t)E * 4);
    const size_t needSort = align256(offCur + NBKT * 4);
    const size_t needProj = align256(offPi + (size_t)n_item * HH * 2);

    const bool sortable = (n_user >= BU) && (n_item >= BI) &&
                          (n_item < 65536) && (n_user / BU + 1 < 65536) &&
                          (n_user <= (1 << 17)) && (ws_size >= needSort);

    const int utiles = (n_user + 63) >> 6;
    const int itiles = (n_item + 63) >> 6;
    const int total  = utiles + itiles;
    const int pgrid  = total < 768 ? total : 768;   // 3 blocks/CU (49 KB LDS)
    const int scatBlocks = (E + SCHUNK - 1) / SCHUNK;

    if (sortable) {
        unsigned short* Wt  = (unsigned short*)((char*)d_ws + offWt);
        unsigned short* Pu  = (unsigned short*)((char*)d_ws + offPu);
        unsigned short* Pi  = (unsigned short*)((char*)d_ws + offPi);
        unsigned*       srt = (unsigned*)((char*)d_ws + offSrt);
        float*          ps  = (float*)((char*)d_ws + offPs);
        unsigned*       inv = (unsigned*)((char*)d_ws + offInv);
        unsigned*       cur = (unsigned*)((char*)d_ws + offCur);

        hipMemsetAsync(cur, 0, NBKT * 4, stream);
        prep_kernel<<<16 + scatBlocks, 256, 0, stream>>>(
            W1, Wt, row, col, cur, srt, inv, E, (unsigned)n_user, (unsigned)n_item, cap);
        project_kernel<<<pgrid, 256, 0, stream>>>(
            z_user, z_item, Wt, b1, Pu, Pi, n_user, n_item, utiles, itiles);
        edge_sorted_kernel<<<2048, 256, 0, stream>>>(Pu, Pi, srt, cur, W2, b2, ps, cap, n_user);
        permute_kernel<<<1024, 256, 0, stream>>>(ps, inv, out, E);
    } else if (ws_size >= needProj) {
        unsigned short* Wt = (unsigned short*)((char*)d_ws + offWt);
        unsigned short* Pu = (unsigned short*)((char*)d_ws + offPu);
        unsigned short* Pi = (unsigned short*)((char*)d_ws + offPi);
        prep_kernel<<<16, 256, 0, stream>>>(
            W1, Wt, row, col, (unsigned*)nullptr, (unsigned*)nullptr, (unsigned*)nullptr,
            0, (unsigned)n_user, (unsigned)n_item, cap);
        project_kernel<<<pgrid, 256, 0, stream>>>(
            z_user, z_item, Wt, b1, Pu, Pi, n_user, n_item, utiles, itiles);
        edge_fp16_kernel<<<2048, 256, 0, stream>>>(Pu, Pi, row, col, W2, b2, out, E);
    } else {
        edge_direct_kernel<<<2048, 256, 0, stream>>>(z_user, z_item, row, col, W1, b1, W2, b2, out, E);
    }
}

// Round 16
// 97.328 us; speedup vs baseline: 1.2007x; 1.2007x over previous
//
#include <hip/hip_runtime.h>

#define HH 128
#define BU 8        // user buckets (one per XCD)
#define BI 32       // item sub-buckets
#define NBKT (BU * BI)
#define SCHUNK 2048 // edges per scatter block
#define GPUC 8192   // edge-kernel 8-lane groups per uc (2048 blocks * 32 / 8)

typedef __attribute__((ext_vector_type(8))) short bf16x8;
typedef __attribute__((ext_vector_type(4))) float f32x4;
typedef _Float16 h2 __attribute__((ext_vector_type(2)));

#if __has_builtin(__builtin_amdgcn_fdot2)
#define FDOT2(a, b, c) __builtin_amdgcn_fdot2((a), (b), (c), false)
#else
#define FDOT2(a, b, c) ((c) + (float)(a)[0] * (float)(b)[0] + (float)(a)[1] * (float)(b)[1])
#endif

__device__ inline unsigned short f2bf(float f) {
    unsigned u = __builtin_bit_cast(unsigned, f);
    u += 0x7FFF + ((u >> 16) & 1);
    return (unsigned short)(u >> 16);
}
__device__ inline unsigned short f2h(float f) {
    return __builtin_bit_cast(unsigned short, (_Float16)f);
}

// ============ prep: blocks 0..15 transpose W -> Wt (SWIZZLED layout); rest: fixed-cap scatter ==
// Wt[h][c*128 + ((kc ^ (c&15))<<3) + (k&7)] = bf16(W1[h*128+k][c])
__global__ __launch_bounds__(256) void prep_kernel(
    const float* __restrict__ W1, unsigned short* __restrict__ Wt,
    const int* __restrict__ row, const int* __restrict__ col,
    unsigned* __restrict__ cursor, unsigned* __restrict__ srt,
    unsigned* __restrict__ invpos, int E, unsigned n_user, unsigned n_item, int cap)
{
    const int t = threadIdx.x;
    if ((int)blockIdx.x < 16) {
        const int gid = blockIdx.x * 256 + t;   // 0..4095
        const int h   = gid >> 11;
        const int c   = (gid >> 4) & 127;
        const int kc  = gid & 15;
        const float* src = W1 + (size_t)(h * 128 + kc * 8) * HH + c;
        unsigned short v[8];
        #pragma unroll
        for (int d = 0; d < 8; ++d)
            v[d] = f2bf(src[(size_t)d * HH]);
        uint4 pack;
        pack.x = (unsigned)v[0] | ((unsigned)v[1] << 16);
        pack.y = (unsigned)v[2] | ((unsigned)v[3] << 16);
        pack.z = (unsigned)v[4] | ((unsigned)v[5] << 16);
        pack.w = (unsigned)v[6] | ((unsigned)v[7] << 16);
        *(uint4*)(Wt + (size_t)h * 16384 + c * 128 + ((kc ^ (c & 15)) << 3)) = pack;
        return;
    }
    // ---- scatter: two-pass block-local LDS binning into fixed-capacity buckets ----
    __shared__ unsigned lh[NBKT];
    __shared__ unsigned gb[NBKT];
    __shared__ unsigned lc[NBKT];
    const int base = ((int)blockIdx.x - 16) * SCHUNK;

    int uu[SCHUNK / 256], ii[SCHUNK / 256];
    lh[t] = 0;
    __syncthreads();
    #pragma unroll
    for (int k = 0; k < SCHUNK / 256; ++k) {
        int e = base + k * 256 + t;
        if (e < E) {
            uu[k] = row[e]; ii[k] = col[e];
            unsigned uc = ((unsigned)uu[k] * BU) / n_user;
            unsigned ic = ((unsigned)ii[k] * BI) / n_item;
            atomicAdd(&lh[uc * BI + ic], 1u);
        }
    }
    __syncthreads();
    gb[t] = lh[t] ? (unsigned)(t * cap) + atomicAdd(&cursor[t], lh[t]) : 0u;
    lc[t] = 0;
    __syncthreads();
    #pragma unroll
    for (int k = 0; k < SCHUNK / 256; ++k) {
        int e = base + k * 256 + t;
        if (e < E) {
            unsigned uc = ((unsigned)uu[k] * BU) / n_user;
            unsigned ic = ((unsigned)ii[k] * BI) / n_item;
            int b = (int)(uc * BI + ic);
            unsigned ucbase = (uc * n_user + 7u) >> 3;
            unsigned r   = atomicAdd(&lc[b], 1u);
            unsigned pos = gb[b] + r;
            srt[pos]  = (((unsigned)uu[k] - ucbase) << 16) | (unsigned)ii[k];
            invpos[e] = pos;
        }
    }
}

// ============ projection: linear LDS stage of pre-swizzled Wt, conflict-free MFMA, fp16 out ====
__global__ __launch_bounds__(256) void project_kernel(
    const float* __restrict__ Zu, const float* __restrict__ Zi,
    const unsigned short* __restrict__ Wt, const float* __restrict__ b1,
    unsigned short* __restrict__ Pu, unsigned short* __restrict__ Pi,
    int n_user, int n_item, int utiles, int itiles)
{
    __shared__ unsigned short sWt[128 * 128];    // 32 KB, swizzle baked into Wt
    __shared__ unsigned short sOut[64 * 136];    // 17 KB

    const int t    = threadIdx.x;
    const int wave = t >> 6;
    const int lane = t & 63;
    const int l16  = lane & 15;
    const int lk8  = (lane >> 4) * 8;
    const int total = utiles + itiles;

    int staged = -1;

    for (int tid = blockIdx.x; tid < total; tid += gridDim.x) {
        const bool isUser = (tid < utiles);
        const int  half   = isUser ? 0 : 1;
        const float* __restrict__ Z = isUser ? Zu : Zi;
        unsigned short* __restrict__ P = isUser ? Pu : Pi;
        const int nrows = isUser ? n_user : n_item;
        const int rbase = (isUser ? tid : (tid - utiles)) << 6;

        if (half != staged) {
            __syncthreads();              // everyone done with old sWt
            const unsigned short* src = Wt + (size_t)half * 16384;
            #pragma unroll
            for (int i = 0; i < 16; ++i) {
                int off = (i * 256 + t) * 8;
                *(uint4*)(sWt + off) = *(const uint4*)(src + off);
            }
            __syncthreads();
            staged = half;
        }

        float b1r[8];
        #pragma unroll
        for (int nt = 0; nt < 8; ++nt)
            b1r[nt] = isUser ? b1[nt * 16 + l16] : 0.f;

        f32x4 acc[8];
        #pragma unroll
        for (int nt = 0; nt < 8; ++nt) acc[nt] = (f32x4)0.f;

        int m = rbase + wave * 16 + l16;
        if (m > nrows - 1) m = nrows - 1;      // clamp tail (stores guarded)
        const float* Zrow = Z + (size_t)m * HH;

        #pragma unroll
        for (int kk = 0; kk < 4; ++kk) {
            float4 z0 = *(const float4*)(Zrow + kk * 32 + lk8);
            float4 z1 = *(const float4*)(Zrow + kk * 32 + lk8 + 4);
            bf16x8 a;
            a[0] = (short)f2bf(z0.x); a[1] = (short)f2bf(z0.y);
            a[2] = (short)f2bf(z0.z); a[3] = (short)f2bf(z0.w);
            a[4] = (short)f2bf(z1.x); a[5] = (short)f2bf(z1.y);
            a[6] = (short)f2bf(z1.z); a[7] = (short)f2bf(z1.w);

            const int chunkSw = ((kk * 4 + (lane >> 4)) ^ l16) << 3;
            #pragma unroll
            for (int nt = 0; nt < 8; ++nt) {
                int c = nt * 16 + l16;
                bf16x8 b = *(const bf16x8*)(sWt + c * 128 + chunkSw);
                acc[nt] = __builtin_amdgcn_mfma_f32_16x16x32_bf16(a, b, acc[nt], 0, 0, 0);
            }
        }

        __syncthreads();   // sOut safe to overwrite
        #pragma unroll
        for (int nt = 0; nt < 8; ++nt) {
            int colc = nt * 16 + l16;
            #pragma unroll
            for (int r = 0; r < 4; ++r) {
                int orow = wave * 16 + (lane >> 4) * 4 + r;
                sOut[orow * 136 + colc] = f2h(acc[nt][r] + b1r[nt]);
            }
        }
        __syncthreads();
        #pragma unroll
        for (int i = 0; i < 4; ++i) {
            int idx = t + i * 256;
            int r   = idx >> 4;
            int ch  = idx & 15;
            int grow = rbase + r;
            if (grow < nrows)
                *(uint4*)(P + (size_t)grow * HH + ch * 8) =
                    *(const uint4*)(sOut + r * 136 + ch * 8);
        }
    }
}

// ============ edge kernel: 8 lanes/edge, fp16 packed math, per-ic padded-bucket sweep ==========
__global__ __launch_bounds__(256) void edge_sorted_kernel(
    const unsigned short* __restrict__ Pu, const unsigned short* __restrict__ Pi,
    const unsigned* __restrict__ srt, const unsigned* __restrict__ cursor,
    const float* __restrict__ W2, const float* __restrict__ b2,
    float* __restrict__ psorted, int cap, int n_user)
{
    const int uc     = blockIdx.x & (BU - 1);
    const int jj     = blockIdx.x >> 3;          // 0..255
    const int g      = threadIdx.x >> 3;         // 0..31
    const int lane8  = threadIdx.x & 7;
    const int gg     = jj * 32 + g;              // 0..8191
    const int c0     = lane8 * 16;               // 16 channels = 32B per lane
    const int ucbase = (int)(((unsigned)uc * (unsigned)n_user + 7u) >> 3);

    h2 w2h[8];
    #pragma unroll
    for (int j = 0; j < 8; ++j) {
        w2h[j][0] = (_Float16)W2[c0 + 2 * j];
        w2h[j][1] = (_Float16)W2[c0 + 2 * j + 1];
    }
    const float b2s = b2[0];
    const h2 hz = {(_Float16)0, (_Float16)0};

    #pragma unroll 1
    for (int ic = 0; ic < BI; ++ic) {
        const int b    = uc * BI + ic;
        const int S    = b * cap;
        const int Tend = S + (int)cursor[b];
        for (int p = S + gg; p < Tend; p += GPUC) {
            unsigned pk = srt[p];
            int u  = ucbase + (int)(pk >> 16);
            int it = (int)(pk & 0xFFFFu);
            const unsigned short* pur = Pu + (size_t)u  * HH + c0;
            const unsigned short* pir = Pi + (size_t)it * HH + c0;
            uint4 a0 = *(const uint4*)pur;
            uint4 a1 = *(const uint4*)(pur + 8);
            uint4 c0v = *(const uint4*)pir;
            uint4 c1v = *(const uint4*)(pir + 8);
            unsigned aw[8] = {a0.x, a0.y, a0.z, a0.w, a1.x, a1.y, a1.z, a1.w};
            unsigned cw[8] = {c0v.x, c0v.y, c0v.z, c0v.w, c1v.x, c1v.y, c1v.z, c1v.w};
            float acc = 0.f;
            #pragma unroll
            for (int q = 0; q < 8; ++q) {
                h2 s = __builtin_bit_cast(h2, aw[q]) + __builtin_bit_cast(h2, cw[q]);
                s = __builtin_elementwise_max(s, hz);
                acc = FDOT2(s, w2h[q], acc);
            }
            acc += __shfl_xor(acc, 4, 64);
            acc += __shfl_xor(acc, 2, 64);
            acc += __shfl_xor(acc, 1, 64);
            if (lane8 == 0) psorted[p] = acc + b2s;
        }
    }
}

// ============ permutation: out[e] = psorted[invpos[e]] ============
__global__ __launch_bounds__(256) void permute_kernel(
    const float* __restrict__ psorted, const unsigned* __restrict__ invpos,
    float* __restrict__ out, int E)
{
    int i  = blockIdx.x * blockDim.x + threadIdx.x;
    int st = gridDim.x * blockDim.x;
    for (int e = i; e < E; e += st)
        out[e] = psorted[invpos[e]];
}

// ============ fallback: unsorted fp16 gather ============
__global__ __launch_bounds__(256) void edge_fp16_kernel(
    const unsigned short* __restrict__ Pu, const unsigned short* __restrict__ Pi,
    const int* __restrict__ row, const int* __restrict__ col,
    const float* __restrict__ W2, const float* __restrict__ b2,
    float* __restrict__ out, int E)
{
    const int lane8  = threadIdx.x & 7;
    const int gid    = (blockIdx.x * blockDim.x + threadIdx.x) >> 3;
    const int stride = (gridDim.x * blockDim.x) >> 3;
    const int c0     = lane8 * 16;

    h2 w2h[8];
    #pragma unroll
    for (int j = 0; j < 8; ++j) {
        w2h[j][0] = (_Float16)W2[c0 + 2 * j];
        w2h[j][1] = (_Float16)W2[c0 + 2 * j + 1];
    }
    const float b2s = b2[0];
    const h2 hz = {(_Float16)0, (_Float16)0};

    for (int e = gid; e < E; e += stride) {
        int u = row[e], it = col[e];
        const unsigned short* pur = Pu + (size_t)u  * HH + c0;
        const unsigned short* pir = Pi + (size_t)it * HH + c0;
        uint4 a0 = *(const uint4*)pur;
        uint4 a1 = *(const uint4*)(pur + 8);
        uint4 c0v = *(const uint4*)pir;
        uint4 c1v = *(const uint4*)(pir + 8);
        unsigned aw[8] = {a0.x, a0.y, a0.z, a0.w, a1.x, a1.y, a1.z, a1.w};
        unsigned cw[8] = {c0v.x, c0v.y, c0v.z, c0v.w, c1v.x, c1v.y, c1v.z, c1v.w};
        float acc = 0.f;
        #pragma unroll
        for (int q = 0; q < 8; ++q) {
            h2 s = __builtin_bit_cast(h2, aw[q]) + __builtin_bit_cast(h2, cw[q]);
            s = __builtin_elementwise_max(s, hz);
            acc = FDOT2(s, w2h[q], acc);
        }
        acc += __shfl_xor(acc, 4, 64);
        acc += __shfl_xor(acc, 2, 64);
        acc += __shfl_xor(acc, 1, 64);
        if (lane8 == 0) out[e] = acc + b2s;
    }
}

// ============ fallback (no workspace): direct per-edge fp32 compute ============
__global__ __launch_bounds__(256) void edge_direct_kernel(
    const float* __restrict__ zu, const float* __restrict__ zi,
    const int* __restrict__ row, const int* __restrict__ col,
    const float* __restrict__ W1, const float* __restrict__ b1,
    const float* __restrict__ W2, const float* __restrict__ b2,
    float* __restrict__ out, int E)
{
    const int lane   = threadIdx.x & 31;
    const int gid    = (blockIdx.x * blockDim.x + threadIdx.x) >> 5;
    const int stride = (gridDim.x * blockDim.x) >> 5;
    const int c0     = lane * 4;

    const float4 b1v = *(const float4*)(b1 + c0);
    const float4 w2v = *(const float4*)(W2 + c0);
    const float  b2s = b2[0];

    for (int e = gid; e < E; e += stride) {
        int u  = row[e];
        int it = col[e];
        const float* zur = zu + (size_t)u  * HH;
        const float* zir = zi + (size_t)it * HH;
        float4 acc = b1v;
        for (int k = 0; k < HH; ++k) {
            float  zk = zur[k];
            float4 w  = *(const float4*)(W1 + (size_t)k * HH + c0);
            acc.x = fmaf(zk, w.x, acc.x);
            acc.y = fmaf(zk, w.y, acc.y);
            acc.z = fmaf(zk, w.z, acc.z);
            acc.w = fmaf(zk, w.w, acc.w);
        }
        for (int k = 0; k < HH; ++k) {
            float  zk = zir[k];
            float4 w  = *(const float4*)(W1 + (size_t)(HH + k) * HH + c0);
            acc.x = fmaf(zk, w.x, acc.x);
            acc.y = fmaf(zk, w.y, acc.y);
            acc.z = fmaf(zk, w.z, acc.z);
            acc.w = fmaf(zk, w.w, acc.w);
        }
        float p = fmaxf(acc.x, 0.f) * w2v.x;
        p = fmaf(fmaxf(acc.y, 0.f), w2v.y, p);
        p = fmaf(fmaxf(acc.z, 0.f), w2v.z, p);
        p = fmaf(fmaxf(acc.w, 0.f), w2v.w, p);
        #pragma unroll
        for (int m = 16; m >= 1; m >>= 1)
            p += __shfl_xor(p, m, 64);
        if (lane == 0) out[e] = p + b2s;
    }
}

static inline size_t align256(size_t x) { return (x + 255) & ~(size_t)255; }

extern "C" void kernel_launch(void* const* d_in, const int* in_sizes, int n_in,
                              void* d_out, int out_size, void* d_ws, size_t ws_size,
                              hipStream_t stream)
{
    const float* z_user = (const float*)d_in[0];
    const float* z_item = (const float*)d_in[1];
    const int*   row    = (const int*)d_in[2];
    const int*   col    = (const int*)d_in[3];
    const float* W1     = (const float*)d_in[4];
    const float* b1     = (const float*)d_in[5];
    const float* W2     = (const float*)d_in[6];
    const float* b2     = (const float*)d_in[7];
    float*       out    = (float*)d_out;

    const int n_user = in_sizes[0] / HH;
    const int n_item = in_sizes[1] / HH;
    const int E      = in_sizes[2];

    // fixed-capacity bucket regions: cap = 1.25*mean + 64
    const int capBase = (E + NBKT - 1) / NBKT;
    const int cap     = capBase + capBase / 4 + 64;
    const size_t padded = (size_t)cap * NBKT;

    // workspace layout
    const size_t offWt  = 0;                                   // 64 KB bf16 W^T (swizzled)
    const size_t offPu  = align256(offWt  + 32768 * 2);
    const size_t offPi  = align256(offPu  + (size_t)n_user * HH * 2);
    const size_t offSrt = align256(offPi  + (size_t)n_item * HH * 2);
    const size_t offPs  = align256(offSrt + padded * 4);
    const size_t offInv = align256(offPs  + padded * 4);
    const size_t offCur = align256(offInv + (size_t)E * 4);
    const size_t needSort = align256(offCur + NBKT * 4);
    const size_t needProj = align256(offPi + (size_t)n_item * HH * 2);

    const bool sortable = (n_user >= BU) && (n_item >= BI) &&
                          (n_item < 65536) && (n_user / BU + 1 < 65536) &&
                          (n_user <= (1 << 17)) && (ws_size >= needSort);

    const int utiles = (n_user + 63) >> 6;
    const int itiles = (n_item + 63) >> 6;
    const int total  = utiles + itiles;
    const int pgrid  = total < 768 ? total : 768;   // 3 blocks/CU (49 KB LDS)
    const int scatBlocks = (E + SCHUNK - 1) / SCHUNK;

    if (sortable) {
        unsigned short* Wt  = (unsigned short*)((char*)d_ws + offWt);
        unsigned short* Pu  = (unsigned short*)((char*)d_ws + offPu);
        unsigned short* Pi  = (unsigned short*)((char*)d_ws + offPi);
        unsigned*       srt = (unsigned*)((char*)d_ws + offSrt);
        float*          ps  = (float*)((char*)d_ws + offPs);
        unsigned*       inv = (unsigned*)((char*)d_ws + offInv);
        unsigned*       cur = (unsigned*)((char*)d_ws + offCur);

        hipMemsetAsync(cur, 0, NBKT * 4, stream);
        prep_kernel<<<16 + scatBlocks, 256, 0, stream>>>(
            W1, Wt, row, col, cur, srt, inv, E, (unsigned)n_user, (unsigned)n_item, cap);
        project_kernel<<<pgrid, 256, 0, stream>>>(
            z_user, z_item, Wt, b1, Pu, Pi, n_user, n_item, utiles, itiles);
        edge_sorted_kernel<<<2048, 256, 0, stream>>>(Pu, Pi, srt, cur, W2, b2, ps, cap, n_user);
        permute_kernel<<<1024, 256, 0, stream>>>(ps, inv, out, E);
    } else if (ws_size >= needProj) {
        unsigned short* Wt = (unsigned short*)((char*)d_ws + offWt);
        unsigned short* Pu = (unsigned short*)((char*)d_ws + offPu);
        unsigned short* Pi = (unsigned short*)((char*)d_ws + offPi);
        prep_kernel<<<16, 256, 0, stream>>>(
            W1, Wt, row, col, (unsigned*)nullptr, (unsigned*)nullptr, (unsigned*)nullptr,
            0, (unsigned)n_user, (unsigned)n_item, cap);
        project_kernel<<<pgrid, 256, 0, stream>>>(
            z_user, z_item, Wt, b1, Pu, Pi, n_user, n_item, utiles, itiles);
        edge_fp16_kernel<<<2048, 256, 0, stream>>>(Pu, Pi, row, col, W2, b2, out, E);
    } else {
        edge_direct_kernel<<<2048, 256, 0, stream>>>(z_user, z_item, row, col, W1, b1, W2, b2, out, E);
    }
}